// Round 1
// baseline (1270.829 us; speedup 1.0000x reference)
//
#include <hip/hip_runtime.h>
#include <stdint.h>

#define N 1024   // 32x32 padded chunk

__device__ __forceinline__ uint32_t f2s(float f) {
    uint32_t u = __float_as_uint(f);
    return (u & 0x80000000u) ? ~u : (u | 0x80000000u);
}
__device__ __forceinline__ float s2f_nonneg(uint32_t s) {
    return __uint_as_float(s & 0x7fffffffu);
}

// One block per (image, chunk). 4 waves: case 0 = -y, 1 = +y, 2 = -x, 3 = +x.
// Cases 0/2 reuse the ascending sort of y/x by walking it in reverse
// (bar-length multiset is tie-order independent; see analysis).
__global__ __launch_bounds__(256) void toploss_chunks(
        const float* __restrict__ xin, const float* __restrict__ yin,
        const int* __restrict__ offs, float* __restrict__ ws)
{
    __shared__ float xc[N], yc[N];
    __shared__ unsigned long long keys[2][N];   // 16 KB: sort scratch (values then lengths)
    __shared__ int par[4][N];                   // 16 KB
    __shared__ float lens[4][N];                // 16 KB
    __shared__ int sh_cnt[4];
    __shared__ float sh_sum[2];

    const int bid = blockIdx.x;      // b*2 + chunk
    const int b = bid >> 1;
    const int tid = threadIdx.x;
    const int off0 = offs[bid * 2 + 0];
    const int off1 = offs[bid * 2 + 1];

    const float* ximg = xin + b * 160000;
    const float* yimg = yin + b * 160000;

    // ---- extract padded chunk + init UF state ----
    for (int s = 0; s < 4; ++s) {
        int idx = tid + 256 * s;
        int i = idx >> 5, j = idx & 31;
        bool border = (i == 0) | (i == 31) | (j == 0) | (j == 31);
        int gi = off0 + i - 1, gj = off1 + j - 1;
        float xv = border ? 1.0f : ximg[gi * 400 + gj];
        float yv = border ? 1.0f : yimg[gi * 400 + gj];
        xc[idx] = xv; yc[idx] = yv;
        par[0][idx] = -1; par[1][idx] = -1; par[2][idx] = -1; par[3][idx] = -1;
        lens[0][idx] = 0.f; lens[1][idx] = 0.f; lens[2][idx] = 0.f; lens[3][idx] = 0.f;
    }
    if (tid < 4) sh_cnt[tid] = 0;
    if (tid < 2) sh_sum[tid] = 0.f;
    __syncthreads();

    // ---- build (value,idx) keys for the two ascending sorts ----
    for (int s = 0; s < 4; ++s) {
        int idx = tid + 256 * s;
        keys[0][idx] = ((unsigned long long)f2s(yc[idx]) << 32) | (unsigned)idx;
        keys[1][idx] = ((unsigned long long)f2s(xc[idx]) << 32) | (unsigned)idx;
    }
    __syncthreads();

    // ---- bitonic sort: threads 0..127 -> keys[0], 128..255 -> keys[1] ----
    {
        unsigned long long* arr = keys[(tid >> 7) & 1];
        int t128 = tid & 127;
        for (int k = 2; k <= N; k <<= 1) {
            for (int j = k >> 1; j > 0; j >>= 1) {
                for (int i = t128; i < N; i += 128) {
                    int l = i ^ j;
                    if (l > i) {
                        unsigned long long a = arr[i], c2 = arr[l];
                        bool up = ((i & k) == 0);
                        if ((a > c2) == up) { arr[i] = c2; arr[l] = a; }
                    }
                }
                __syncthreads();
            }
        }
    }

    // ---- serial elder-rule union-find sweep: lane 0 of each wave ----
    const int c = tid >> 6;
    if ((tid & 63) == 0) {
        const int img = c >> 1;                       // 0=y, 1=x
        const float sgn = (c & 1) ? 1.0f : -1.0f;
        const float* base = img ? xc : yc;
        int* P = par[c];
        float* L = lens[c];
        const unsigned long long* K = keys[img];
        const int DI[6] = {-1, 1, 0, 0, 1, -1};
        const int DJ[6] = { 0, 0,-1, 1, 1, -1};
        for (int t = 0; t < N; ++t) {
            int pos = (c & 1) ? t : (N - 1 - t);      // reverse walk = sort of -v
            int u = (int)(K[pos] & 1023ull);
            float val = sgn * base[u];
            P[u] = u;
            int ru = u; float bu = val;
            int ui = u >> 5, uj = u & 31;
            int nbv[6], pn[6], q[6];
            #pragma unroll
            for (int d = 0; d < 6; ++d) {
                int ni = ui + DI[d], nj = uj + DJ[d];
                bool ok = (ni >= 0) & (ni < 32) & (nj >= 0) & (nj < 32);
                nbv[d] = ok ? ((ni << 5) | nj) : -1;
            }
            #pragma unroll
            for (int d = 0; d < 6; ++d)               // batched level-0 reads
                pn[d] = (nbv[d] >= 0) ? P[nbv[d]] : -1;
            #pragma unroll
            for (int d = 0; d < 6; ++d)               // batched level-1 reads
                q[d] = (pn[d] >= 0) ? P[pn[d]] : -1;
            #pragma unroll
            for (int d = 0; d < 6; ++d) {
                if (pn[d] < 0) continue;              // off-grid or not inserted
                int r = pn[d], p = q[d];
                while (p != r) {                      // find root, path-halving
                    int gp = P[p];
                    P[r] = gp;
                    r = gp;
                    p = P[r];
                }
                P[nbv[d]] = r;                        // path compression
                if (r == ru) continue;
                float br = sgn * base[r];
                bool uelder = (bu < br) || ((bu == br) && (ru <= r));
                if (uelder) {                          // neighbor comp dies
                    L[r] = val - br;
                    P[r] = ru;
                } else {                               // our comp dies
                    L[ru] = val - bu;
                    P[ru] = r;
                    ru = r; bu = br;
                }
            }
        }
    }
    __syncthreads();

    // ---- count nonzero bars per case ----
    {
        int cnt = 0;
        const float* L = lens[c];
        for (int s = 0; s < 16; ++s)
            cnt += (L[(tid & 63) + 64 * s] > 0.f) ? 1 : 0;
        atomicAdd(&sh_cnt[c], cnt);
    }
    __syncthreads();

    // ---- sort input-case bar lengths ascending (reuse keys buffers) ----
    for (int s = 0; s < 4; ++s) {
        int idx = tid + 256 * s;
        keys[0][idx] = ((unsigned long long)f2s(lens[2][idx]) << 32);
        keys[1][idx] = ((unsigned long long)f2s(lens[3][idx]) << 32);
    }
    __syncthreads();
    {
        unsigned long long* arr = keys[(tid >> 7) & 1];
        int t128 = tid & 127;
        for (int k = 2; k <= N; k <<= 1) {
            for (int j = k >> 1; j > 0; j >>= 1) {
                for (int i = t128; i < N; i += 128) {
                    int l = i ^ j;
                    if (l > i) {
                        unsigned long long a = arr[i], c2 = arr[l];
                        bool up = ((i & k) == 0);
                        if ((a > c2) == up) { arr[i] = c2; arr[l] = a; }
                    }
                }
                __syncthreads();
            }
        }
    }

    // ---- partial sums: skip prior largest == keep (N - prior) smallest ----
    {
        int prior0 = sh_cnt[0] + 1;   // +1: infinite essential dim-0 bar
        int prior1 = sh_cnt[1];
        int grp = (tid >> 7) & 1;
        int keep = N - (grp ? prior1 : prior0);
        unsigned long long* arr = keys[grp];
        int t128 = tid & 127;
        float sum = 0.f;
        for (int i = t128; i < N; i += 128)
            if (i < keep) sum += s2f_nonneg((uint32_t)(arr[i] >> 32));
        atomicAdd(&sh_sum[grp], sum);
    }
    __syncthreads();
    if (tid == 0) ws[bid] = sh_sum[0] + sh_sum[1];
}

__global__ void toploss_reduce(const float* __restrict__ ws, float* __restrict__ out) {
    if (threadIdx.x == 0) {
        float s = 0.f;
        for (int i = 0; i < 8; ++i) s += ws[i];
        out[0] = s * 0.125f;   // mean over B of mean over chunks = sum/8
    }
}

extern "C" void kernel_launch(void* const* d_in, const int* in_sizes, int n_in,
                              void* d_out, int out_size, void* d_ws, size_t ws_size,
                              hipStream_t stream) {
    const float* x = (const float*)d_in[0];
    const float* y = (const float*)d_in[1];
    const int* offs = (const int*)d_in[2];
    float* out = (float*)d_out;
    float* ws = (float*)d_ws;
    toploss_chunks<<<8, 256, 0, stream>>>(x, y, offs, ws);
    toploss_reduce<<<1, 64, 0, stream>>>(ws, out);
}

// Round 2
// 270.316 us; speedup vs baseline: 4.7013x; 4.7013x over previous
//
#include <hip/hip_runtime.h>
#include <stdint.h>

#define EMPTY 0xFFFFFFFFu
#define HSZ 2048
#define LCAP 1024
#define WREG 516   // per-diagram ws floats: [0]=pos count,[1]=total,[4..515]=lengths

__device__ __forceinline__ uint32_t f2s(float f) {
    uint32_t u = __float_as_uint(f);
    return (u & 0x80000000u) ? ~u : (u | 0x80000000u);
}
__device__ __forceinline__ float s2f(uint32_t s) {
    uint32_t u = (s & 0x80000000u) ? (s & 0x7fffffffu) : ~s;
    return __uint_as_float(u);
}

// One block per diagram: bid = chunk*4 + c; c: 0=-y,1=+y,2=-x,3=+x
__global__ __launch_bounds__(256) void pd_kernel(
        const float* __restrict__ xin, const float* __restrict__ yin,
        const int* __restrict__ offs, float* __restrict__ ws)
{
    __shared__ float v[1024];              // signed chunk values
    __shared__ unsigned short sd[1024];    // steepest-descent -> basin label
    __shared__ unsigned short P[1024];     // UF parent over basin roots
    __shared__ uint32_t hpair[HSZ];        // hash: basin pair (a<<10|b), EMPTY=free
    __shared__ uint32_t hw[HSZ];           // hash: min edge weight (f2s key)
    __shared__ unsigned long long elist[LCAP];
    __shared__ int ecnt;

    const int bid = blockIdx.x;
    const int q = bid >> 2, c = bid & 3;
    const int b = q >> 1;
    const int tid = threadIdx.x;
    const float sgn = (c & 1) ? 1.0f : -1.0f;
    const float* img = (c >> 1) ? (xin + b * 160000) : (yin + b * 160000);
    const int off0 = offs[q * 2 + 0], off1 = offs[q * 2 + 1];

    // ---- load signed values with +1.0 contour border (sign applied) ----
    for (int s = 0; s < 4; ++s) {
        int u = tid + 256 * s;
        int i = u >> 5, j = u & 31;
        bool border = (i == 0) | (i == 31) | (j == 0) | (j == 31);
        float val = border ? 1.0f : img[(off0 + i - 1) * 400 + (off1 + j - 1)];
        v[u] = sgn * val;
    }
    for (int s = 0; s < HSZ; s += 256) { hpair[tid + s] = EMPTY; hw[tid + s] = EMPTY; }
    if (tid == 0) ecnt = 0;
    __syncthreads();

    // ---- steepest descent: min lower neighbor in (f2s,idx) total order ----
    const int DI[6] = {-1, 1, 0, 0, 1, -1};
    const int DJ[6] = { 0, 0,-1, 1, 1, -1};
    for (int s = 0; s < 4; ++s) {
        int u = tid + 256 * s;
        int i = u >> 5, j = u & 31;
        unsigned long long best = ((unsigned long long)f2s(v[u]) << 10) | (unsigned)u;
        int bi = u;
        #pragma unroll
        for (int d = 0; d < 6; ++d) {
            int ni = i + DI[d], nj = j + DJ[d];
            if (ni < 0 || ni > 31 || nj < 0 || nj > 31) continue;
            int nb = (ni << 5) | nj;
            unsigned long long kn = ((unsigned long long)f2s(v[nb]) << 10) | (unsigned)nb;
            if (kn < best) { best = kn; bi = nb; }
        }
        sd[u] = (unsigned short)bi;
    }
    __syncthreads();
    // ---- pointer doubling -> basin min label (in-place jumping is monotone) ----
    for (int r = 0; r < 10; ++r) {
        for (int s = 0; s < 4; ++s) {
            int u = tid + 256 * s;
            sd[u] = sd[sd[u]];
        }
        __syncthreads();
    }

    // ---- inter-basin edges, deduped per pair with min weight (hash+atomicMin) ----
    const int CDI[3] = {1, 0, 1}, CDJ[3] = {0, 1, 1};   // canonical undirected dirs
    for (int s = 0; s < 4; ++s) {
        int u = tid + 256 * s;
        int i = u >> 5, j = u & 31;
        uint32_t fu = f2s(v[u]);
        #pragma unroll
        for (int d = 0; d < 3; ++d) {
            int ni = i + CDI[d], nj = j + CDJ[d];
            if (ni > 31 || nj > 31) continue;
            int nb = (ni << 5) | nj;
            int a = sd[u], bb = sd[nb];
            if (a == bb) continue;
            uint32_t fn = f2s(v[nb]);
            uint32_t w = (fn > fu || (fn == fu && nb > u)) ? fn : fu;  // later endpoint
            uint32_t p = (a < bb) ? (((uint32_t)a << 10) | bb) : (((uint32_t)bb << 10) | a);
            uint32_t h = (p * 2654435761u) >> 21;   // 11-bit slot
            while (true) {
                uint32_t old = atomicCAS(&hpair[h], EMPTY, p);
                if (old == EMPTY || old == p) { atomicMin(&hw[h], w); break; }
                h = (h + 1) & (HSZ - 1);
            }
        }
    }
    __syncthreads();
    // ---- compact hash -> edge list ----
    for (int s = 0; s < HSZ; s += 256) {
        int h = tid + s;
        if (hpair[h] != EMPTY) {
            int e = atomicAdd(&ecnt, 1);
            if (e < LCAP) elist[e] = ((unsigned long long)hw[h] << 20) | hpair[h];
        }
    }
    __syncthreads();
    int m = ecnt; if (m > LCAP) m = LCAP;
    for (int i = tid; i < LCAP; i += 256) if (i >= m) elist[i] = ~0ull;
    __syncthreads();

    // ---- bitonic sort edges ascending by (weight, pair) ----
    for (int k = 2; k <= LCAP; k <<= 1) {
        for (int j = k >> 1; j > 0; j >>= 1) {
            for (int i = tid; i < LCAP; i += 256) {
                int l = i ^ j;
                if (l > i) {
                    unsigned long long A = elist[i], B = elist[l];
                    bool up = ((i & k) == 0);
                    if ((A > B) == up) { elist[i] = B; elist[l] = A; }
                }
            }
            __syncthreads();
        }
    }

    // ---- init UF + zero output region ----
    float* wreg = ws + bid * WREG;
    for (int s = 0; s < 4; ++s) { int u = tid + 256 * s; P[u] = (unsigned short)u; }
    for (int i = tid; i < WREG; i += 256) wreg[i] = 0.0f;
    __syncthreads();

    // ---- serial elder-rule Kruskal over ~440 deduped edges ----
    if (tid == 0) {
        int cnt = 0, pos = 0;
        float tot = 0.0f;
        for (int e = 0; e < m; ++e) {
            unsigned long long rec = elist[e];
            int a = (int)((rec >> 10) & 1023);
            int b2 = (int)(rec & 1023);
            int ra = a;
            while (true) { int p1 = P[ra]; if (p1 == ra) break; int p2 = P[p1]; P[ra] = (unsigned short)p2; ra = p2; }
            int rb = b2;
            while (true) { int p1 = P[rb]; if (p1 == rb) break; int p2 = P[p1]; P[rb] = (unsigned short)p2; rb = p2; }
            if (ra == rb) continue;
            uint32_t ka = f2s(v[ra]), kb = f2s(v[rb]);
            bool aeld = (ka < kb) || (ka == kb && ra < rb);
            int eld = aeld ? ra : rb;
            int yng = aeld ? rb : ra;
            float val = s2f((uint32_t)(rec >> 20));
            float len = val - v[yng];          // birth of young = its basin-min value
            P[yng] = (unsigned short)eld;
            if (cnt < 512) wreg[4 + cnt] = len;
            cnt++;
            if (len > 0.0f) pos++;
            tot += len;
        }
        wreg[0] = (float)pos;
        wreg[1] = tot;
    }
}

// One block per chunk: combine 4 diagrams into the chunk loss.
__global__ __launch_bounds__(256) void loss_kernel(const float* __restrict__ ws,
                                                   float* __restrict__ ws2)
{
    __shared__ uint32_t sk[2][512];
    __shared__ float ssum[2];
    const int q = blockIdx.x, tid = threadIdx.x;
    const float* r0 = ws + (q * 4 + 0) * WREG;
    const float* r1 = ws + (q * 4 + 1) * WREG;
    const float* r2 = ws + (q * 4 + 2) * WREG;
    const float* r3 = ws + (q * 4 + 3) * WREG;
    int prior0 = (int)r0[0] + 1;   // +1: infinite essential dim-0 bar
    int prior1 = (int)r1[0];
    for (int s = tid; s < 512; s += 256) {
        sk[0][s] = f2s(r2[4 + s]);
        sk[1][s] = f2s(r3[4 + s]);
    }
    if (tid < 2) ssum[tid] = 0.0f;
    __syncthreads();
    // bitonic ascending; threads <128 -> case2 array, >=128 -> case3 array
    uint32_t* arr = sk[(tid >> 7) & 1];
    int t = tid & 127;
    for (int k = 2; k <= 512; k <<= 1) {
        for (int j = k >> 1; j > 0; j >>= 1) {
            for (int i = t; i < 512; i += 128) {
                int l = i ^ j;
                if (l > i) {
                    uint32_t A = arr[i], B = arr[l];
                    bool up = ((i & k) == 0);
                    if ((A > B) == up) { arr[i] = B; arr[l] = A; }
                }
            }
            __syncthreads();
        }
    }
    // loss_c = total_c - sum(top prior entries)
    int grp = (tid >> 7) & 1;
    int pr = grp ? prior1 : prior0; if (pr > 512) pr = 512;
    float s = 0.0f;
    for (int i = t; i < 512; i += 128)
        if (i >= 512 - pr) s += s2f(arr[i]);
    atomicAdd(&ssum[grp], s);
    __syncthreads();
    if (tid == 0)
        ws2[q] = (r2[1] - ssum[0]) + (r3[1] - ssum[1]);
}

__global__ void reduce_kernel(const float* __restrict__ ws2, float* __restrict__ out) {
    if (threadIdx.x == 0) {
        float s = 0.0f;
        for (int i = 0; i < 8; ++i) s += ws2[i];
        out[0] = s * 0.125f;
    }
}

extern "C" void kernel_launch(void* const* d_in, const int* in_sizes, int n_in,
                              void* d_out, int out_size, void* d_ws, size_t ws_size,
                              hipStream_t stream) {
    const float* x = (const float*)d_in[0];
    const float* y = (const float*)d_in[1];
    const int* offs = (const int*)d_in[2];
    float* w = (float*)d_ws;
    float* w2 = w + 32 * WREG;
    pd_kernel<<<32, 256, 0, stream>>>(x, y, offs, w);
    loss_kernel<<<8, 256, 0, stream>>>(w, w2);
    reduce_kernel<<<1, 64, 0, stream>>>(w2, (float*)d_out);
}

// Round 3
// 217.632 us; speedup vs baseline: 5.8393x; 1.2421x over previous
//
#include <hip/hip_runtime.h>
#include <stdint.h>

#define INFK 0xFFFFFFFFu

__device__ __forceinline__ uint32_t f2s(float f) {
    uint32_t u = __float_as_uint(f);
    return (u & 0x80000000u) ? ~u : (u | 0x80000000u);
}
__device__ __forceinline__ float s2f(uint32_t s) {
    uint32_t u = (s & 0x80000000u) ? (s & 0x7fffffffu) : ~s;
    return __uint_as_float(u);
}

// One block per (image,chunk). The 4 diagrams (c: 0=-y,1=+y,2=-x,3=+x) run
// sequentially; H0 pairing is computed by a fully parallel lock-free triplet
// merge-tree over basin minima (no serial union-find, no edge sort).
__global__ __launch_bounds__(256) void toploss_fused(
        const float* __restrict__ xin, const float* __restrict__ yin,
        const int* __restrict__ offs, float* __restrict__ out)
{
    __shared__ float vb[1024];                 // unsigned chunk values
    __shared__ float v[1024];                  // signed values for current case
    __shared__ unsigned short sd[1024];        // steepest-descent -> basin min vertex
    __shared__ unsigned short ranktab[1024];   // basin min vertex -> dense rank
    __shared__ unsigned short minvert[256];    // rank -> vertex
    __shared__ unsigned long long bku[256];    // rank -> birth key (f2s<<10 | idx)
    __shared__ unsigned long long trip[256];   // rank -> (death_key<<32 | elder_rank)
    __shared__ uint32_t lst[2][256];           // positive bar keys for cases 2,3
    __shared__ float tots[2];
    __shared__ int priors[2];
    __shared__ float ssum[2];
    __shared__ int cnt, npos, nslot, flag;
    __shared__ float ftot;

    const int q = blockIdx.x;                  // b*2 + chunk
    const int b = q >> 1;
    const int tid = threadIdx.x;
    const int off0 = offs[q * 2 + 0], off1 = offs[q * 2 + 1];

    for (int s = tid; s < 256; s += 256) { lst[0][s] = 0x80000000u; lst[1][s] = 0x80000000u; }
    __syncthreads();

    const int DI[6] = {-1, 1, 0, 0, 1, -1};
    const int DJ[6] = { 0, 0,-1, 1, 1, -1};
    const int CDI[3] = {1, 0, 1}, CDJ[3] = {0, 1, 1};

    for (int c = 0; c < 4; ++c) {
        // ---- load base chunk (y at c==0, x at c==2), +1.0 contour border ----
        if ((c & 1) == 0) {
            const float* img = (c >> 1) ? (xin + b * 160000) : (yin + b * 160000);
            for (int s = 0; s < 4; ++s) {
                int u = tid + 256 * s;
                int i = u >> 5, j = u & 31;
                bool border = (i == 0) | (i == 31) | (j == 0) | (j == 31);
                vb[u] = border ? 1.0f : img[(off0 + i - 1) * 400 + (off1 + j - 1)];
            }
        }
        __syncthreads();
        const float sgn = (c & 1) ? 1.0f : -1.0f;
        for (int s = 0; s < 4; ++s) { int u = tid + 256 * s; v[u] = sgn * vb[u]; }
        if (tid == 0) { cnt = 0; npos = 0; nslot = 0; ftot = 0.f; }
        __syncthreads();

        // ---- steepest descent pointer (strict total order (f2s,idx)) ----
        for (int s = 0; s < 4; ++s) {
            int u = tid + 256 * s;
            int i = u >> 5, j = u & 31;
            unsigned long long best = ((unsigned long long)f2s(v[u]) << 10) | (unsigned)u;
            int bi = u;
            #pragma unroll
            for (int d = 0; d < 6; ++d) {
                int ni = i + DI[d], nj = j + DJ[d];
                if (ni < 0 || ni > 31 || nj < 0 || nj > 31) continue;
                int nb = (ni << 5) | nj;
                unsigned long long kn = ((unsigned long long)f2s(v[nb]) << 10) | (unsigned)nb;
                if (kn < best) { best = kn; bi = nb; }
            }
            sd[u] = (unsigned short)bi;
        }
        __syncthreads();

        // ---- pointer jumping to basin min (adaptive; races are benign) ----
        while (true) {
            if (tid == 0) flag = 0;
            __syncthreads();
            bool ch = false;
            for (int s = 0; s < 4; ++s) {
                int u = tid + 256 * s;
                int s1 = sd[u], s2 = sd[s1];
                if (s2 != s1) { sd[u] = (unsigned short)s2; ch = true; }
            }
            if (ch) flag = 1;
            __syncthreads();
            if (!flag) break;
        }

        // ---- dense rank the minima; init triplets ----
        for (int s = 0; s < 4; ++s) {
            int u = tid + 256 * s;
            if (sd[u] == u) {
                int r = atomicAdd(&cnt, 1);
                ranktab[u] = (unsigned short)r;
                minvert[r] = (unsigned short)u;
                bku[r] = ((unsigned long long)f2s(v[u]) << 10) | (unsigned)u;
                trip[r] = ((unsigned long long)INFK << 32) | (unsigned)r;
            }
        }
        __syncthreads();

        // ---- lock-free triplet merges over all cross-basin edges ----
        for (int s = 0; s < 4; ++s) {
            int u = tid + 256 * s;
            int i = u >> 5, j = u & 31;
            uint32_t ku = f2s(v[u]);
            #pragma unroll
            for (int d = 0; d < 3; ++d) {
                int ni = i + CDI[d], nj = j + CDJ[d];
                if (ni > 31 || nj > 31) continue;
                int nb = (ni << 5) | nj;
                int sa = sd[u], sb = sd[nb];
                if (sa == sb) continue;
                uint32_t kn = f2s(v[nb]);
                uint32_t w = (ku > kn) ? ku : kn;     // lower-star edge value
                int a = ranktab[sa], bb = ranktab[sb];
                while (true) {
                    int ra = a;
                    while (true) {
                        unsigned long long t = *(volatile unsigned long long*)&trip[ra];
                        uint32_t sv = (uint32_t)(t >> 32);
                        if (sv > w) break;
                        ra = (int)(t & 0xFFFFu);
                    }
                    int rb = bb;
                    while (true) {
                        unsigned long long t = *(volatile unsigned long long*)&trip[rb];
                        uint32_t sv = (uint32_t)(t >> 32);
                        if (sv > w) break;
                        rb = (int)(t & 0xFFFFu);
                    }
                    if (ra == rb) break;
                    int y, e;
                    if (bku[ra] < bku[rb]) { e = ra; y = rb; } else { e = rb; y = ra; }
                    unsigned long long old = *(volatile unsigned long long*)&trip[y];
                    uint32_t sy = (uint32_t)(old >> 32);
                    if (sy <= w) continue;            // concurrent change; re-walk
                    unsigned long long nw = ((unsigned long long)w << 32) | (unsigned)e;
                    if (atomicCAS(&trip[y], old, nw) == old) {
                        if (sy == INFK) break;        // no displaced fact
                        a = y; bb = (int)(old & 0xFFFFu); w = sy;  // re-insert it
                    }
                    // CAS failure: retry loop
                }
            }
        }
        __syncthreads();

        // ---- bars: len = death - birth; count/total/collect positives ----
        if (tid < cnt) {
            unsigned long long t = trip[tid];
            uint32_t sv = (uint32_t)(t >> 32);
            if (sv != INFK) {
                float len = s2f(sv) - v[minvert[tid]];
                if (len > 0.0f) {
                    atomicAdd(&npos, 1);
                    atomicAdd(&ftot, len);
                    if (c >= 2) {
                        int sl = atomicAdd(&nslot, 1);
                        if (sl < 256) lst[c - 2][sl] = f2s(len);
                    }
                }
            }
        }
        __syncthreads();
        if (tid == 0) {
            if (c == 0) priors[0] = npos + 1;   // +1: infinite essential dim-0 bar
            else if (c == 1) priors[1] = npos;
            else tots[c - 2] = ftot;
        }
        __syncthreads();
    }

    // ---- sort positive bars ascending (two 256-lists, half-block each) ----
    {
        uint32_t* arr = lst[(tid >> 7) & 1];
        int t = tid & 127;
        for (int k = 2; k <= 256; k <<= 1) {
            for (int j = k >> 1; j > 0; j >>= 1) {
                for (int i = t; i < 256; i += 128) {
                    int l = i ^ j;
                    if (l > i) {
                        uint32_t A = arr[i], B = arr[l];
                        bool up = ((i & k) == 0);
                        if ((A > B) == up) { arr[i] = B; arr[l] = A; }
                    }
                }
                __syncthreads();
            }
        }
    }

    // ---- chunk loss = (tot2 - top prior0) + (tot3 - top prior1) ----
    if (tid < 2) ssum[tid] = 0.f;
    __syncthreads();
    {
        int grp = (tid >> 7) & 1;
        int pr = priors[grp]; if (pr > 256) pr = 256;
        uint32_t* arr = lst[grp];
        int t = tid & 127;
        float s = 0.f;
        for (int i = t; i < 256; i += 128)
            if (i >= 256 - pr) s += s2f(arr[i]);
        atomicAdd(&ssum[grp], s);
    }
    __syncthreads();
    if (tid == 0) {
        float loss = (tots[0] - ssum[0]) + (tots[1] - ssum[1]);
        atomicAdd(out, loss * 0.125f);
    }
}

extern "C" void kernel_launch(void* const* d_in, const int* in_sizes, int n_in,
                              void* d_out, int out_size, void* d_ws, size_t ws_size,
                              hipStream_t stream) {
    const float* x = (const float*)d_in[0];
    const float* y = (const float*)d_in[1];
    const int* offs = (const int*)d_in[2];
    hipMemsetAsync(d_out, 0, sizeof(float), stream);
    toploss_fused<<<8, 256, 0, stream>>>(x, y, offs, (float*)d_out);
}

// Round 4
// 216.654 us; speedup vs baseline: 5.8657x; 1.0045x over previous
//
#include <hip/hip_runtime.h>
#include <stdint.h>

#define INFK 0xFFFFFFFFu

__device__ __forceinline__ uint32_t f2s(float f) {
    uint32_t u = __float_as_uint(f);
    return (u & 0x80000000u) ? ~u : (u | 0x80000000u);
}
__device__ __forceinline__ float s2f(uint32_t s) {
    uint32_t u = (s & 0x80000000u) ? (s & 0x7fffffffu) : ~s;
    return __uint_as_float(u);
}

// Lock-free triplet merge-tree insertion (identical logic to round 3).
__device__ __forceinline__ void tmerge(unsigned long long* trip,
                                       const unsigned long long* bku,
                                       int a, int b, uint32_t w) {
    while (true) {
        int ra = a;
        while (true) {
            unsigned long long t = *(volatile unsigned long long*)&trip[ra];
            uint32_t sv = (uint32_t)(t >> 32);
            if (sv > w) break;
            ra = (int)(t & 0xFFFFu);
        }
        int rb = b;
        while (true) {
            unsigned long long t = *(volatile unsigned long long*)&trip[rb];
            uint32_t sv = (uint32_t)(t >> 32);
            if (sv > w) break;
            rb = (int)(t & 0xFFFFu);
        }
        if (ra == rb) return;
        int y, e;
        if (bku[ra] < bku[rb]) { e = ra; y = rb; } else { e = rb; y = ra; }
        unsigned long long old = *(volatile unsigned long long*)&trip[y];
        uint32_t sy = (uint32_t)(old >> 32);
        if (sy <= w) continue;                 // concurrent change; re-walk
        unsigned long long nw = ((unsigned long long)w << 32) | (unsigned)e;
        if (atomicCAS(&trip[y], old, nw) == old) {
            if (sy == INFK) return;            // no displaced fact
            a = y; b = (int)(old & 0xFFFFu); w = sy;   // re-insert displaced fact
        }
    }
}

// One block per (image,chunk); the 4 diagrams (0=-y,1=+y,2=-x,3=+x) are
// computed CONCURRENTLY, phase-interleaved, for 4x ILP and 1/4 the barriers.
// Case keys derive from kx/ky by bit-complement: f2s(-v) == ~f2s(v).
__global__ __launch_bounds__(256) void toploss_fused(
        const float* __restrict__ xin, const float* __restrict__ yin,
        const int* __restrict__ offs, float* __restrict__ out)
{
    __shared__ uint32_t kx[1024], ky[1024];        // f2s sort keys of raw chunks
    __shared__ unsigned short sd[4][1024];         // steepest-descent pointers
    __shared__ unsigned short rnk[4][1024];        // basin-min vertex -> dense rank
    __shared__ unsigned long long bku[4][256];     // rank -> birth key (key<<10|idx)
    __shared__ unsigned long long trip[4][256];    // rank -> (death<<32 | elder)
    __shared__ uint32_t lst[2][256];               // positive bar keys, cases 2,3
    __shared__ int cnt4[4], npos4[4], nslot2[2], priors[2];
    __shared__ float ftot4[4], ssum[2];

    const int q = blockIdx.x;                      // b*2 + chunk
    const int b = q >> 1;
    const int tid = threadIdx.x;
    const int off0 = offs[q * 2 + 0], off1 = offs[q * 2 + 1];
    const float* ximg = xin + b * 160000;
    const float* yimg = yin + b * 160000;

    if (tid < 4) { cnt4[tid] = 0; npos4[tid] = 0; ftot4[tid] = 0.f; }
    if (tid < 2) { nslot2[tid] = 0; ssum[tid] = 0.f; }
    lst[0][tid] = 0x80000000u;                     // f2s(0.0f)
    lst[1][tid] = 0x80000000u;

    // ---- load chunk keys with +1.0 contour border ----
    for (int s = 0; s < 4; ++s) {
        int u = tid + 256 * s;
        int i = u >> 5, j = u & 31;
        bool border = (i == 0) | (i == 31) | (j == 0) | (j == 31);
        int g = (off0 + i - 1) * 400 + (off1 + j - 1);
        kx[u] = f2s(border ? 1.0f : ximg[g]);
        ky[u] = f2s(border ? 1.0f : yimg[g]);
    }
    __syncthreads();

    const int DI[6] = {-1, 1, 0, 0, 1, -1};
    const int DJ[6] = { 0, 0,-1, 1, 1, -1};

    // ---- steepest descent for all 4 cases at once ----
    for (int s = 0; s < 4; ++s) {
        int u = tid + 256 * s;
        int i = u >> 5, j = u & 31;
        uint32_t kxu = kx[u], kyu = ky[u];
        uint32_t myk[4] = {~kyu, kyu, ~kxu, kxu};
        unsigned long long best[4];
        int bi[4];
        #pragma unroll
        for (int c = 0; c < 4; ++c) {
            best[c] = ((unsigned long long)myk[c] << 10) | (unsigned)u;
            bi[c] = u;
        }
        #pragma unroll
        for (int d = 0; d < 6; ++d) {
            int ni = i + DI[d], nj = j + DJ[d];
            if (ni < 0 || ni > 31 || nj < 0 || nj > 31) continue;
            int nb = (ni << 5) | nj;
            uint32_t kxn = kx[nb], kyn = ky[nb];
            uint32_t nk[4] = {~kyn, kyn, ~kxn, kxn};
            #pragma unroll
            for (int c = 0; c < 4; ++c) {
                unsigned long long kn = ((unsigned long long)nk[c] << 10) | (unsigned)nb;
                if (kn < best[c]) { best[c] = kn; bi[c] = nb; }
            }
        }
        #pragma unroll
        for (int c = 0; c < 4; ++c) sd[c][u] = (unsigned short)bi[c];
    }
    __syncthreads();

    // ---- pointer jumping to basin min (in-place, monotone; 2^10 >= any path) ----
    for (int r = 0; r < 10; ++r) {
        for (int s = 0; s < 4; ++s) {
            int u = tid + 256 * s;
            #pragma unroll
            for (int c = 0; c < 4; ++c) sd[c][u] = sd[c][sd[c][u]];
        }
        __syncthreads();
    }

    // ---- dense-rank minima; init triplets ----
    for (int s = 0; s < 4; ++s) {
        int u = tid + 256 * s;
        uint32_t kxu = kx[u], kyu = ky[u];
        uint32_t myk[4] = {~kyu, kyu, ~kxu, kxu};
        #pragma unroll
        for (int c = 0; c < 4; ++c) {
            if (sd[c][u] == u) {
                int r = atomicAdd(&cnt4[c], 1);
                rnk[c][u] = (unsigned short)r;
                bku[c][r] = ((unsigned long long)myk[c] << 10) | (unsigned)u;
                trip[c][r] = ((unsigned long long)INFK << 32) | (unsigned)r;
            }
        }
    }
    __syncthreads();

    // ---- lock-free triplet merges over all cross-basin edges, all cases ----
    const int CDI[3] = {1, 0, 1}, CDJ[3] = {0, 1, 1};
    for (int s = 0; s < 4; ++s) {
        int u = tid + 256 * s;
        int i = u >> 5, j = u & 31;
        uint32_t kxu = kx[u], kyu = ky[u];
        uint32_t myk[4] = {~kyu, kyu, ~kxu, kxu};
        #pragma unroll
        for (int d = 0; d < 3; ++d) {
            int ni = i + CDI[d], nj = j + CDJ[d];
            if (ni > 31 || nj > 31) continue;
            int nb = (ni << 5) | nj;
            uint32_t kxn = kx[nb], kyn = ky[nb];
            uint32_t nk[4] = {~kyn, kyn, ~kxn, kxn};
            #pragma unroll
            for (int c = 0; c < 4; ++c) {
                int sa = sd[c][u], sb = sd[c][nb];
                if (sa == sb) continue;
                uint32_t w = (myk[c] > nk[c]) ? myk[c] : nk[c];
                tmerge(trip[c], bku[c], rnk[c][sa], rnk[c][sb], w);
            }
        }
    }
    __syncthreads();

    // ---- bars: count positives, totals, collect input-case lengths ----
    #pragma unroll
    for (int c = 0; c < 4; ++c) {
        if (tid < cnt4[c]) {
            unsigned long long t = trip[c][tid];
            uint32_t sv = (uint32_t)(t >> 32);
            if (sv != INFK) {
                float len = s2f(sv) - s2f((uint32_t)(bku[c][tid] >> 10));
                if (len > 0.0f) {
                    atomicAdd(&npos4[c], 1);
                    atomicAdd(&ftot4[c], len);
                    if (c >= 2) {
                        int sl = atomicAdd(&nslot2[c - 2], 1);
                        if (sl < 256) lst[c - 2][sl] = f2s(len);
                    }
                }
            }
        }
    }
    __syncthreads();
    if (tid == 0) {
        priors[0] = npos4[0] + 1;   // +1: infinite essential dim-0 bar
        priors[1] = npos4[1];
    }
    __syncthreads();

    // ---- sort positive bars ascending (two 256-lists, half-block each) ----
    {
        uint32_t* arr = lst[(tid >> 7) & 1];
        int t = tid & 127;
        for (int k = 2; k <= 256; k <<= 1) {
            for (int j = k >> 1; j > 0; j >>= 1) {
                for (int i = t; i < 256; i += 128) {
                    int l = i ^ j;
                    if (l > i) {
                        uint32_t A = arr[i], B = arr[l];
                        bool up = ((i & k) == 0);
                        if ((A > B) == up) { arr[i] = B; arr[l] = A; }
                    }
                }
                __syncthreads();
            }
        }
    }

    // ---- chunk loss = (tot2 - top prior0) + (tot3 - top prior1) ----
    {
        int grp = (tid >> 7) & 1;
        int pr = priors[grp]; if (pr > 256) pr = 256;
        uint32_t* arr = lst[grp];
        int t = tid & 127;
        float s = 0.f;
        for (int i = t; i < 256; i += 128)
            if (i >= 256 - pr) s += s2f(arr[i]);
        atomicAdd(&ssum[grp], s);
    }
    __syncthreads();
    if (tid == 0) {
        float loss = (ftot4[2] - ssum[0]) + (ftot4[3] - ssum[1]);
        atomicAdd(out, loss * 0.125f);
    }
}

extern "C" void kernel_launch(void* const* d_in, const int* in_sizes, int n_in,
                              void* d_out, int out_size, void* d_ws, size_t ws_size,
                              hipStream_t stream) {
    const float* x = (const float*)d_in[0];
    const float* y = (const float*)d_in[1];
    const int* offs = (const int*)d_in[2];
    hipMemsetAsync(d_out, 0, sizeof(float), stream);
    toploss_fused<<<8, 256, 0, stream>>>(x, y, offs, (float*)d_out);
}

// Round 5
// 197.919 us; speedup vs baseline: 6.4210x; 1.0947x over previous
//
#include <hip/hip_runtime.h>
#include <stdint.h>

#define EMPTY 0xFFFFFFFFu
#define HSZ 2048
#define WSTRIDE 392   // per-diagram floats in ws: [0]=npos,[1]=tot,[2]=nbars,[8..]=bars

__device__ __forceinline__ uint32_t f2s(float f) {
    uint32_t u = __float_as_uint(f);
    return (u & 0x80000000u) ? ~u : (u | 0x80000000u);
}
__device__ __forceinline__ float s2f(uint32_t s) {
    uint32_t u = (s & 0x80000000u) ? (s & 0x7fffffffu) : ~s;
    return __uint_as_float(u);
}

// One block per diagram (bid = chunk*4 + c; c: 0=-y,1=+y,2=-x,3=+x).
// Basins via steepest descent + pointer jumping; saddle edges deduped with a
// per-pair atomicMin hash; sorted (block bitonic); elder-rule Kruskal with the
// union-find held ENTIRELY in wave-0 registers (flat labels, no LDS chains).
__global__ __launch_bounds__(256) void pd_kernel(
        const float* __restrict__ xin, const float* __restrict__ yin,
        const int* __restrict__ offs, float* __restrict__ ws,
        float* __restrict__ out)
{
    __shared__ uint32_t key[1024];            // case-signed sort keys (f2s)
    __shared__ unsigned short sd[1024];       // steepest-descent -> basin min vertex
    __shared__ unsigned short rnk[1024];      // basin min vertex -> dense rank
    __shared__ uint32_t minkey[512];          // rank -> basin min key
    __shared__ uint32_t hpair[HSZ], hw[HSZ];  // pair-dedup hash (min weight)
    __shared__ unsigned long long elist[1024];
    __shared__ int cnt, ecnt;

    const int bid = blockIdx.x;
    const int q = bid >> 2, c = bid & 3;
    const int b = q >> 1;
    const int tid = threadIdx.x;
    const int off0 = offs[q * 2 + 0], off1 = offs[q * 2 + 1];
    const float* img = (c >> 1) ? (xin + b * 160000) : (yin + b * 160000);
    const bool neg = !(c & 1);

    if (bid == 0 && tid == 0) out[0] = 0.0f;  // pre-zero for loss_kernel atomics
    if (tid == 0) { cnt = 0; ecnt = 0; }
    for (int s = tid; s < HSZ; s += 256) { hpair[s] = EMPTY; hw[s] = EMPTY; }

    // ---- load chunk with +1.0 contour border; key = f2s(+/-v) via ~ trick ----
    for (int s = 0; s < 4; ++s) {
        int u = tid + 256 * s;
        int i = u >> 5, j = u & 31;
        bool border = (i == 0) | (i == 31) | (j == 0) | (j == 31);
        float val = border ? 1.0f : img[(off0 + i - 1) * 400 + (off1 + j - 1)];
        uint32_t k = f2s(val);
        key[u] = neg ? ~k : k;                // f2s(-v) == ~f2s(v)
    }
    __syncthreads();

    // ---- steepest descent (strict total order (key,idx)) ----
    const int DI[6] = {-1, 1, 0, 0, 1, -1};
    const int DJ[6] = { 0, 0,-1, 1, 1, -1};
    for (int s = 0; s < 4; ++s) {
        int u = tid + 256 * s;
        int i = u >> 5, j = u & 31;
        unsigned long long best = ((unsigned long long)key[u] << 10) | (unsigned)u;
        int bi = u;
        #pragma unroll
        for (int d = 0; d < 6; ++d) {
            int ni = i + DI[d], nj = j + DJ[d];
            if (ni < 0 || ni > 31 || nj < 0 || nj > 31) continue;
            int nb = (ni << 5) | nj;
            unsigned long long kn = ((unsigned long long)key[nb] << 10) | (unsigned)nb;
            if (kn < best) { best = kn; bi = nb; }
        }
        sd[u] = (unsigned short)bi;
    }
    __syncthreads();

    // ---- pointer jumping to basin min (monotone; 2^10 covers any chain) ----
    for (int r = 0; r < 10; ++r) {
        for (int s = 0; s < 4; ++s) { int u = tid + 256 * s; sd[u] = sd[sd[u]]; }
        __syncthreads();
    }

    // ---- dense-rank minima ----
    for (int s = 0; s < 4; ++s) {
        int u = tid + 256 * s;
        if (sd[u] == (unsigned short)u) {
            int r = atomicAdd(&cnt, 1);
            rnk[u] = (unsigned short)r;
            minkey[r] = key[u];
        }
    }
    __syncthreads();

    // ---- cross-basin edges, per-pair min weight via hash ----
    const int CDI[3] = {1, 0, 1}, CDJ[3] = {0, 1, 1};
    for (int s = 0; s < 4; ++s) {
        int u = tid + 256 * s;
        int i = u >> 5, j = u & 31;
        uint32_t ku = key[u];
        int sa = sd[u];
        #pragma unroll
        for (int d = 0; d < 3; ++d) {
            int ni = i + CDI[d], nj = j + CDJ[d];
            if (ni > 31 || nj > 31) continue;
            int nb = (ni << 5) | nj;
            int sb = sd[nb];
            if (sa == sb) continue;
            uint32_t kn = key[nb];
            uint32_t w = ku > kn ? ku : kn;           // later endpoint's value key
            int a = rnk[sa], bb = rnk[sb];
            if (a > bb) { int t = a; a = bb; bb = t; }
            uint32_t pk = ((uint32_t)a << 9) | (uint32_t)bb;
            uint32_t h = (pk * 2654435761u) >> 21;
            while (true) {
                uint32_t old = atomicCAS(&hpair[h], EMPTY, pk);
                if (old == EMPTY || old == pk) { atomicMin(&hw[h], w); break; }
                h = (h + 1) & (HSZ - 1);
            }
        }
    }
    __syncthreads();

    // ---- compact hash -> edge list ----
    for (int s = tid; s < HSZ; s += 256) {
        if (hpair[s] != EMPTY) {
            int e = atomicAdd(&ecnt, 1);
            elist[e] = ((unsigned long long)hw[s] << 18) | hpair[s];
        }
    }
    __syncthreads();
    const int m = ecnt;                         // deduped pairs <= 3*nb-6 <= 1017
    const int msort = (m <= 512) ? 512 : 1024;
    for (int s = tid; s < 1024; s += 256) if (s >= m && s < msort) elist[s] = ~0ull;
    __syncthreads();

    // ---- block bitonic sort ascending by (weight, pair) ----
    for (int k = 2; k <= msort; k <<= 1) {
        for (int jj = k >> 1; jj > 0; jj >>= 1) {
            for (int i2 = tid; i2 < msort; i2 += 256) {
                int l = i2 ^ jj;
                if (l > i2) {
                    unsigned long long A = elist[i2], B = elist[l];
                    bool up = ((i2 & k) == 0);
                    if ((A > B) == up) { elist[i2] = B; elist[l] = A; }
                }
            }
            __syncthreads();
        }
    }

    // ---- elder-rule Kruskal, union-find in wave-0 REGISTERS (flat labels) ----
    if (tid < 64) {
        const int lane = tid;
        // label for rank r (lane = r&63, slot = r>>6): elder's (key<<9 | rank)
        unsigned long long l0, l1, l2, l3, l4, l5;
        {
            int r;
            r = lane;       l0 = (r < cnt) ? ((unsigned long long)minkey[r] << 9) | (unsigned)r : (0xFFFFFFFFull << 9) | (unsigned)r;
            r = lane + 64;  l1 = (r < cnt) ? ((unsigned long long)minkey[r] << 9) | (unsigned)r : (0xFFFFFFFFull << 9) | (unsigned)r;
            r = lane + 128; l2 = (r < cnt) ? ((unsigned long long)minkey[r] << 9) | (unsigned)r : (0xFFFFFFFFull << 9) | (unsigned)r;
            r = lane + 192; l3 = (r < cnt) ? ((unsigned long long)minkey[r] << 9) | (unsigned)r : (0xFFFFFFFFull << 9) | (unsigned)r;
            r = lane + 256; l4 = (r < cnt) ? ((unsigned long long)minkey[r] << 9) | (unsigned)r : (0xFFFFFFFFull << 9) | (unsigned)r;
            r = lane + 320; l5 = (r < cnt) ? ((unsigned long long)minkey[r] << 9) | (unsigned)r : (0xFFFFFFFFull << 9) | (unsigned)r;
        }
        int npos = 0, nbars = 0;
        float tot = 0.0f;
        float* wbase = ws + bid * WSTRIDE;

        for (int base = 0; base < m; base += 64) {
            int nn = m - base; if (nn > 64) nn = 64;
            unsigned long long myrec = elist[base + (lane < nn ? lane : 0)];
            for (int i2 = 0; i2 < nn; ++i2) {
                unsigned long long rec =
                    (unsigned long long)__shfl((long long)myrec, i2, 64);
                int a = (int)((rec >> 9) & 511u), bb = (int)(rec & 511u);
                int ka = a >> 6, kb = bb >> 6;
                unsigned long long va = l0;
                va = (ka == 1) ? l1 : va; va = (ka == 2) ? l2 : va;
                va = (ka == 3) ? l3 : va; va = (ka == 4) ? l4 : va;
                va = (ka == 5) ? l5 : va;
                unsigned long long La =
                    (unsigned long long)__shfl((long long)va, a & 63, 64);
                unsigned long long vb = l0;
                vb = (kb == 1) ? l1 : vb; vb = (kb == 2) ? l2 : vb;
                vb = (kb == 3) ? l3 : vb; vb = (kb == 4) ? l4 : vb;
                vb = (kb == 5) ? l5 : vb;
                unsigned long long Lb =
                    (unsigned long long)__shfl((long long)vb, bb & 63, 64);
                if (La == Lb) continue;                 // same component (dup/cycle)
                unsigned long long yg = (La > Lb) ? La : Lb;   // younger root
                unsigned long long el = (La > Lb) ? Lb : La;   // elder root
                float len = s2f((uint32_t)(rec >> 18)) - s2f((uint32_t)(yg >> 9));
                if (len > 0.0f) {
                    if (lane == 0) wbase[8 + nbars] = len;
                    nbars++; npos++; tot += len;
                }
                l0 = (l0 == yg) ? el : l0;              // flat relabel, no chains
                l1 = (l1 == yg) ? el : l1;
                l2 = (l2 == yg) ? el : l2;
                l3 = (l3 == yg) ? el : l3;
                l4 = (l4 == yg) ? el : l4;
                l5 = (l5 == yg) ? el : l5;
            }
        }
        if (lane == 0) {
            wbase[0] = (float)npos;
            wbase[1] = tot;
            wbase[2] = (float)nbars;
        }
    }
}

// One block per chunk: sort the 2 input-case bar lists, partial sums, loss.
__global__ __launch_bounds__(256) void loss_kernel(const float* __restrict__ ws,
                                                   float* __restrict__ out)
{
    __shared__ uint32_t lst[2][512];
    __shared__ float ssum[2];
    const int q = blockIdx.x, tid = threadIdx.x;
    const float* r0 = ws + (q * 4 + 0) * WSTRIDE;
    const float* r1 = ws + (q * 4 + 1) * WSTRIDE;
    const float* r2 = ws + (q * 4 + 2) * WSTRIDE;
    const float* r3 = ws + (q * 4 + 3) * WSTRIDE;
    const int prior0 = (int)r0[0] + 1;      // +1: infinite essential dim-0 bar
    const int prior1 = (int)r1[0];
    const int nb2 = (int)r2[2], nb3 = (int)r3[2];
    for (int s = tid; s < 512; s += 256) {
        lst[0][s] = (s < nb2) ? __float_as_uint(r2[8 + s]) : 0u;  // positive floats:
        lst[1][s] = (s < nb3) ? __float_as_uint(r3[8 + s]) : 0u;  // uint order = float order
    }
    if (tid < 2) ssum[tid] = 0.0f;
    __syncthreads();
    // bitonic ascending; threads <128 -> list0, >=128 -> list1
    uint32_t* arr = lst[(tid >> 7) & 1];
    int t = tid & 127;
    for (int k = 2; k <= 512; k <<= 1) {
        for (int j = k >> 1; j > 0; j >>= 1) {
            for (int i = t; i < 512; i += 128) {
                int l = i ^ j;
                if (l > i) {
                    uint32_t A = arr[i], B = arr[l];
                    bool up = ((i & k) == 0);
                    if ((A > B) == up) { arr[i] = B; arr[l] = A; }
                }
            }
            __syncthreads();
        }
    }
    {
        int grp = (tid >> 7) & 1;
        int pr = grp ? prior1 : prior0; if (pr > 512) pr = 512;
        float s = 0.0f;
        for (int i = t; i < 512; i += 128)
            if (i >= 512 - pr) s += __uint_as_float(arr[i]);
        atomicAdd(&ssum[grp], s);
    }
    __syncthreads();
    if (tid == 0) {
        float loss = (r2[1] - ssum[0]) + (r3[1] - ssum[1]);
        atomicAdd(out, loss * 0.125f);
    }
}

extern "C" void kernel_launch(void* const* d_in, const int* in_sizes, int n_in,
                              void* d_out, int out_size, void* d_ws, size_t ws_size,
                              hipStream_t stream) {
    const float* x = (const float*)d_in[0];
    const float* y = (const float*)d_in[1];
    const int* offs = (const int*)d_in[2];
    float* w = (float*)d_ws;
    pd_kernel<<<32, 256, 0, stream>>>(x, y, offs, w, (float*)d_out);
    loss_kernel<<<8, 256, 0, stream>>>(w, (float*)d_out);
}